// Round 7
// baseline (156.456 us; speedup 1.0000x reference)
//
#include <hip/hip_runtime.h>

#define B_ 2
#define N_ 16384
#define M_ 8192

typedef float f32x4 __attribute__((ext_vector_type(4)));
typedef short s16x8 __attribute__((ext_vector_type(8)));

__device__ inline float min3f(float a, float b, float c) {
    float d;
    asm("v_min3_f32 %0, %1, %2, %3" : "=v"(d) : "v"(a), "v"(b), "v"(c));
    return d;
}

// RNE f32 -> bf16 (bits)
__device__ inline unsigned short f2bf(float f) {
    unsigned int u = __float_as_uint(f);
    u += 0x7FFFu + ((u >> 16) & 1u);
    return (unsigned short)(u >> 16);
}
__device__ inline float bf2f(unsigned short h) {
    return __uint_as_float(((unsigned int)h) << 16);
}
// 3-way bf16 split: v ~= h + m + l to ~2^-24 rel
__device__ inline void split3(float v, unsigned short& hb, unsigned short& mb,
                              unsigned short& lb) {
    hb = f2bf(v);
    float r1 = v - bf2f(hb);
    mb = f2bf(r1);
    float r2 = r1 - bf2f(mb);
    lb = f2bf(r2);
}

// ---------------- reductions ----------------

__device__ inline float blk_reduce_max(float v, float* red) {
    #pragma unroll
    for (int off = 32; off; off >>= 1) v = fmaxf(v, __shfl_xor(v, off));
    int wid = threadIdx.x >> 6;
    int lane = threadIdx.x & 63;
    int nw = blockDim.x >> 6;
    if (lane == 0) red[wid] = v;
    __syncthreads();
    if (wid == 0) {
        v = (lane < nw) ? red[lane] : -3.402823466e38f;
        #pragma unroll
        for (int off = 32; off; off >>= 1) v = fmaxf(v, __shfl_xor(v, off));
        if (lane == 0) red[0] = v;
    }
    __syncthreads();
    v = red[0];
    __syncthreads();
    return v;
}

__device__ inline float blk_reduce_sum(float v, float* red) {
    #pragma unroll
    for (int off = 32; off; off >>= 1) v += __shfl_xor(v, off);
    int wid = threadIdx.x >> 6;
    int lane = threadIdx.x & 63;
    int nw = blockDim.x >> 6;
    if (lane == 0) red[wid] = v;
    __syncthreads();
    if (wid == 0) {
        v = (lane < nw) ? red[lane] : 0.0f;
        #pragma unroll
        for (int off = 32; off; off >>= 1) v += __shfl_xor(v, off);
        if (lane == 0) red[0] = v;
    }
    __syncthreads();
    v = red[0];
    __syncthreads();
    return v;
}

// ---------------- kernels ----------------

__global__ __launch_bounds__(256) void init_ws(const float* __restrict__ wts,
                                               unsigned int* min1, unsigned int* min2,
                                               float* __restrict__ wmax_part,
                                               float* out) {
    int i = blockIdx.x * 256 + threadIdx.x;
    if (i < B_ * N_) min1[i] = 0x7F7FFFFFu;  // FLT_MAX bits
    if (i < B_ * M_) min2[i] = 0x7F7FFFFFu;
    if (i == 0) out[0] = 0.0f;

    float v = wts[i];
    #pragma unroll
    for (int off = 32; off; off >>= 1) v = fmaxf(v, __shfl_xor(v, off));
    if ((threadIdx.x & 63) == 0)
        wmax_part[blockIdx.x * 4 + (threadIdx.x >> 6)] = v;  // 4 waves/block
}

// Single-pass MFMA chamfer sweep — same verified math as rounds 4/6 (absmax
// 0.0): K slots 0-17 = 6 product groups of 3-way bf16 splits of u=-2x and y;
// slots 18-23 = sq1 split x 1, 1 x sq2 split; 24-31 zero (groups stored 0-2
// only, lanes 48-63 substitute zfrag -> MFMA inputs bit-identical).
//
// ROUND-7 CHANGE (de-serialize the mt loop): round-6 showed residency stuck
// at ~2.8 blocks/CU regardless of LDS limit (34.7% occ at both 36KB and
// 24KB), both pipes ~50% idle -> waves are latency-bound on the in-loop
// chain: ds_read -> MFMA -> 8-deep min3 -> TWO shfl_xor (lgkm is IN-ORDER
// for DS, so each shuffle wait also drains the pipelined Bsh prefetch) ->
// atomic. Fix: keep per-lane min2 partials in 16 REGISTERS (m2p[mt], fully
// unrolled = static indexing), shallow tree min in-loop, NO ds/atomic ops in
// the loop. Cross-lane reduce + LDS combine (Ash reused as 4KB scratch) +
// one atomic per column move to the epilogue (atomics back to 256/block =
// round-4 count, undoing round-6's 4x WRITE_SIZE regression).
__global__ __launch_bounds__(256) void chamfer_mfma(
        const float* __restrict__ p1, const float* __restrict__ p2,
        unsigned int* __restrict__ min1, unsigned int* __restrict__ min2) {
    __shared__ s16x8 Ash[16][48];        // 12KB; reused as m2 scratch post-loop
    __shared__ s16x8 Bsh[16][48];        // 12KB

    const int bid = blockIdx.x;
    const int b   = bid >> 11;           // 2048 blocks per batch
    const int rr  = bid & 2047;
    const int ob  = rr >> 5;             // 64 owner blocks
    const int bin = rr & 31;             // 32 scan bins
    const int nb  = ob * 256;
    const int mb  = bin * 256;

    const int t = threadIdx.x;
    const short ONE = (short)0x3F80;     // bf16(1.0)

    // ---- stage A: owner rows (u = -2x, sq1 = x.x) ----
    {
        const float* px = p1 + ((size_t)b * N_ + nb + t) * 3;
        float x0 = px[0], x1 = px[1], x2 = px[2];
        float sq = fmaf(x0, x0, fmaf(x1, x1, x2 * x2));
        unsigned short uh[3], um[3], ul[3], s1[3];
        split3(-2.f * x0, uh[0], um[0], ul[0]);
        split3(-2.f * x1, uh[1], um[1], ul[1]);
        split3(-2.f * x2, uh[2], um[2], ul[2]);
        split3(sq, s1[0], s1[1], s1[2]);
        s16x8 g0 = {(short)uh[0], (short)uh[1], (short)uh[2], (short)uh[0],
                    (short)uh[1], (short)uh[2], (short)um[0], (short)um[1]};
        s16x8 g1 = {(short)um[2], (short)uh[0], (short)uh[1], (short)uh[2],
                    (short)ul[0], (short)ul[1], (short)ul[2], (short)um[0]};
        s16x8 g2 = {(short)um[1], (short)um[2], (short)s1[0], (short)s1[1],
                    (short)s1[2], ONE, ONE, ONE};
        int tl = t >> 4, c = t & 15;
        Ash[tl][ 0 + c] = g0;
        Ash[tl][16 + c] = g1;
        Ash[tl][32 + c] = g2;
    }
    // ---- stage B: scanned cols (y, sq2 = y.y) ----
    {
        const float* py = p2 + ((size_t)b * M_ + mb + t) * 3;
        float y0 = py[0], y1 = py[1], y2 = py[2];
        float sq = fmaf(y0, y0, fmaf(y1, y1, y2 * y2));
        unsigned short yh[3], ym[3], yl[3], s2[3];
        split3(y0, yh[0], ym[0], yl[0]);
        split3(y1, yh[1], ym[1], yl[1]);
        split3(y2, yh[2], ym[2], yl[2]);
        split3(sq, s2[0], s2[1], s2[2]);
        s16x8 g0 = {(short)yh[0], (short)yh[1], (short)yh[2], (short)ym[0],
                    (short)ym[1], (short)ym[2], (short)yh[0], (short)yh[1]};
        s16x8 g1 = {(short)yh[2], (short)yl[0], (short)yl[1], (short)yl[2],
                    (short)yh[0], (short)yh[1], (short)yh[2], (short)ym[0]};
        s16x8 g2 = {(short)ym[1], (short)ym[2], ONE, ONE, ONE,
                    (short)s2[0], (short)s2[1], (short)s2[2]};
        int tl = t >> 4, c = t & 15;
        Bsh[tl][ 0 + c] = g0;
        Bsh[tl][16 + c] = g1;
        Bsh[tl][32 + c] = g2;
    }
    __syncthreads();

    const int w = t >> 6, l = t & 63;
    const s16x8 zfrag = {0, 0, 0, 0, 0, 0, 0, 0};

    s16x8 Af[4];
    #pragma unroll
    for (int r = 0; r < 4; r++)
        Af[r] = (l < 48) ? Ash[4 * w + r][l] : zfrag;   // group 3 == zeros

    f32x4 mn1v[4];
    #pragma unroll
    for (int r = 0; r < 4; r++)
        mn1v[r] = (f32x4){3.402823466e38f, 3.402823466e38f,
                          3.402823466e38f, 3.402823466e38f};

    const f32x4 zacc = {0.f, 0.f, 0.f, 0.f};
    float m2p[16];   // per-lane min2 partials, static-indexed via full unroll

    #pragma unroll
    for (int mt = 0; mt < 16; mt++) {
        s16x8 Bf = (l < 48) ? Bsh[mt][l] : zfrag;       // group 3 == zeros
        float pr[4];
        #pragma unroll
        for (int r = 0; r < 4; r++) {
            f32x4 acc = __builtin_amdgcn_mfma_f32_16x16x32_bf16(Af[r], Bf, zacc, 0, 0, 0);
            mn1v[r].x = fminf(mn1v[r].x, acc.x);
            mn1v[r].y = fminf(mn1v[r].y, acc.y);
            mn1v[r].z = fminf(mn1v[r].z, acc.z);
            mn1v[r].w = fminf(mn1v[r].w, acc.w);
            pr[r] = fminf(min3f(acc.x, acc.y, acc.z), acc.w);
        }
        m2p[mt] = fminf(fminf(pr[0], pr[1]), fminf(pr[2], pr[3]));
    }

    // ---- epilogue: min1 (reduce over the 16 cols held across lanes l&15) ----
    unsigned int* m1g = min1 + (size_t)b * N_;
    #pragma unroll
    for (int r = 0; r < 4; r++) {
        #pragma unroll
        for (int q = 0; q < 4; q++) {
            float v = mn1v[r][q];
            v = fminf(v, __shfl_xor(v, 1));
            v = fminf(v, __shfl_xor(v, 2));
            v = fminf(v, __shfl_xor(v, 4));
            v = fminf(v, __shfl_xor(v, 8));
            if ((l & 15) == 0) {
                int row = nb + (4 * w + r) * 16 + (l >> 4) * 4 + q;
                // distances non-negative: float bits order as uint
                atomicMin(&m1g[row], __float_as_uint(v));
            }
        }
    }

    // ---- epilogue: min2 (cross-rowgroup shfl + LDS combine, 256 atomics) ----
    __syncthreads();                      // all waves done reading Ash/Bsh
    float* scr = (float*)Ash;             // [4][16][16] = 4KB scratch
    #pragma unroll
    for (int mt = 0; mt < 16; mt++) {
        float v = m2p[mt];
        v = fminf(v, __shfl_xor(v, 16));  // independent, pipelineable
        v = fminf(v, __shfl_xor(v, 32));
        if (l < 16) scr[(w * 16 + mt) * 16 + l] = v;
    }
    __syncthreads();
    {
        int mt = t >> 4, c = t & 15;
        float v = fminf(fminf(scr[(0 * 16 + mt) * 16 + c],
                              scr[(1 * 16 + mt) * 16 + c]),
                        fminf(scr[(2 * 16 + mt) * 16 + c],
                              scr[(3 * 16 + mt) * 16 + c]));
        atomicMin(&min2[(size_t)b * M_ + mb + mt * 16 + c], __float_as_uint(v));
    }
}

__global__ __launch_bounds__(1024) void finalize_kernel(
        const float* __restrict__ wts,
        const float* __restrict__ min1,
        const float* __restrict__ min2,
        const float* __restrict__ wmax_part,
        float* __restrict__ out) {
    __shared__ float red[16];
    int b = blockIdx.x;
    const float* wb = wts + b * N_;
    const float* m1 = min1 + b * N_;
    const float* m2 = min2 + b * M_;

    float lmax = (threadIdx.x < 256) ? wmax_part[b * 256 + threadIdx.x]
                                     : -3.402823466e38f;
    float gmax = blk_reduce_max(lmax, red);

    float se = 0.0f, swm = 0.0f;
    for (int i = threadIdx.x; i < N_ / 4; i += blockDim.x) {
        f32x4 w4 = ((const f32x4*)wb)[i];
        f32x4 m4 = ((const f32x4*)m1)[i];
        #pragma unroll
        for (int k = 0; k < 4; k++) {
            float e = expf(w4[k] - gmax);
            se += e;
            swm += e * m4[k];
        }
    }
    float tse = blk_reduce_sum(se, red);
    float tswm = blk_reduce_sum(swm, red);

    float sm2 = 0.0f;
    for (int i = threadIdx.x; i < M_ / 4; i += blockDim.x) {
        f32x4 m4 = ((const f32x4*)m2)[i];
        sm2 += (m4.x + m4.y) + (m4.z + m4.w);
    }
    float tsm2 = blk_reduce_sum(sm2, red);

    if (threadIdx.x == 0)
        atomicAdd(out, (tswm / tse + tsm2 * (1.0f / (float)M_)) * (1.0f / (float)B_));
}

// ---------------- launch ----------------

extern "C" void kernel_launch(void* const* d_in, const int* in_sizes, int n_in,
                              void* d_out, int out_size, void* d_ws, size_t ws_size,
                              hipStream_t stream) {
    const float* p1  = (const float*)d_in[0];  // (B, N, 3)
    const float* p2  = (const float*)d_in[1];  // (B, M, 3)
    const float* wts = (const float*)d_in[2];  // (B, N)
    float* out = (float*)d_out;

    unsigned int* min1 = (unsigned int*)d_ws;        // B*N
    unsigned int* min2 = min1 + B_ * N_;             // B*M
    float* wmax_part = (float*)(min2 + B_ * M_);     // 128 blocks * 4 waves = 512

    init_ws<<<dim3((B_ * N_) / 256), dim3(256), 0, stream>>>(wts, min1, min2,
                                                             wmax_part, out);
    chamfer_mfma<<<dim3(4096), dim3(256), 0, stream>>>(p1, p2, min1, min2);
    finalize_kernel<<<dim3(B_), dim3(1024), 0, stream>>>(
        wts, (const float*)min1, (const float*)min2, wmax_part, out);
}

// Round 8
// 50.371 us; speedup vs baseline: 3.1060x; 3.1060x over previous
//
#include <hip/hip_runtime.h>

#define B_ 2
#define N_ 16384
#define M_ 8192
#define CH 4                      // scan chunks per block (4*256 = 1024 cols)

typedef float f32x4 __attribute__((ext_vector_type(4)));
typedef short s16x8 __attribute__((ext_vector_type(8)));

__device__ inline float min3f(float a, float b, float c) {
    float d;
    asm("v_min3_f32 %0, %1, %2, %3" : "=v"(d) : "v"(a), "v"(b), "v"(c));
    return d;
}

// RNE f32 -> bf16 (bits)
__device__ inline unsigned short f2bf(float f) {
    unsigned int u = __float_as_uint(f);
    u += 0x7FFFu + ((u >> 16) & 1u);
    return (unsigned short)(u >> 16);
}
__device__ inline float bf2f(unsigned short h) {
    return __uint_as_float(((unsigned int)h) << 16);
}
// 3-way bf16 split: v ~= h + m + l to ~2^-24 rel
__device__ inline void split3(float v, unsigned short& hb, unsigned short& mb,
                              unsigned short& lb) {
    hb = f2bf(v);
    float r1 = v - bf2f(hb);
    mb = f2bf(r1);
    float r2 = r1 - bf2f(mb);
    lb = f2bf(r2);
}

#define ONE_BF ((short)0x3F80)

// fragment builders — verbatim slot maps from the verified rounds 4/6 kernel
__device__ inline void buildA(float x0, float x1, float x2,
                              s16x8& g0, s16x8& g1, s16x8& g2) {
    float sq = fmaf(x0, x0, fmaf(x1, x1, x2 * x2));
    unsigned short uh[3], um[3], ul[3], s1[3];
    split3(-2.f * x0, uh[0], um[0], ul[0]);
    split3(-2.f * x1, uh[1], um[1], ul[1]);
    split3(-2.f * x2, uh[2], um[2], ul[2]);
    split3(sq, s1[0], s1[1], s1[2]);
    g0 = (s16x8){(short)uh[0], (short)uh[1], (short)uh[2], (short)uh[0],
                 (short)uh[1], (short)uh[2], (short)um[0], (short)um[1]};
    g1 = (s16x8){(short)um[2], (short)uh[0], (short)uh[1], (short)uh[2],
                 (short)ul[0], (short)ul[1], (short)ul[2], (short)um[0]};
    g2 = (s16x8){(short)um[1], (short)um[2], (short)s1[0], (short)s1[1],
                 (short)s1[2], ONE_BF, ONE_BF, ONE_BF};
}
__device__ inline void buildB(float y0, float y1, float y2,
                              s16x8& g0, s16x8& g1, s16x8& g2) {
    float sq = fmaf(y0, y0, fmaf(y1, y1, y2 * y2));
    unsigned short yh[3], ym[3], yl[3], s2[3];
    split3(y0, yh[0], ym[0], yl[0]);
    split3(y1, yh[1], ym[1], yl[1]);
    split3(y2, yh[2], ym[2], yl[2]);
    split3(sq, s2[0], s2[1], s2[2]);
    g0 = (s16x8){(short)yh[0], (short)yh[1], (short)yh[2], (short)ym[0],
                 (short)ym[1], (short)ym[2], (short)yh[0], (short)yh[1]};
    g1 = (s16x8){(short)yh[2], (short)yl[0], (short)yl[1], (short)yl[2],
                 (short)yh[0], (short)yh[1], (short)yh[2], (short)ym[0]};
    g2 = (s16x8){(short)ym[1], (short)ym[2], ONE_BF, ONE_BF, ONE_BF,
                 (short)s2[0], (short)s2[1], (short)s2[2]};
}

// ---------------- reductions ----------------

__device__ inline float blk_reduce_max(float v, float* red) {
    #pragma unroll
    for (int off = 32; off; off >>= 1) v = fmaxf(v, __shfl_xor(v, off));
    int wid = threadIdx.x >> 6;
    int lane = threadIdx.x & 63;
    int nw = blockDim.x >> 6;
    if (lane == 0) red[wid] = v;
    __syncthreads();
    if (wid == 0) {
        v = (lane < nw) ? red[lane] : -3.402823466e38f;
        #pragma unroll
        for (int off = 32; off; off >>= 1) v = fmaxf(v, __shfl_xor(v, off));
        if (lane == 0) red[0] = v;
    }
    __syncthreads();
    v = red[0];
    __syncthreads();
    return v;
}

__device__ inline float blk_reduce_sum(float v, float* red) {
    #pragma unroll
    for (int off = 32; off; off >>= 1) v += __shfl_xor(v, off);
    int wid = threadIdx.x >> 6;
    int lane = threadIdx.x & 63;
    int nw = blockDim.x >> 6;
    if (lane == 0) red[wid] = v;
    __syncthreads();
    if (wid == 0) {
        v = (lane < nw) ? red[lane] : 0.0f;
        #pragma unroll
        for (int off = 32; off; off >>= 1) v += __shfl_xor(v, off);
        if (lane == 0) red[0] = v;
    }
    __syncthreads();
    v = red[0];
    __syncthreads();
    return v;
}

// ---------------- kernels ----------------

__global__ __launch_bounds__(256) void init_ws(const float* __restrict__ wts,
                                               unsigned int* min1, unsigned int* min2,
                                               float* __restrict__ wmax_part,
                                               float* out) {
    int i = blockIdx.x * 256 + threadIdx.x;
    if (i < B_ * N_) min1[i] = 0x7F7FFFFFu;  // FLT_MAX bits
    if (i < B_ * M_) min2[i] = 0x7F7FFFFFu;
    if (i == 0) out[0] = 0.0f;

    float v = wts[i];
    #pragma unroll
    for (int off = 32; off; off >>= 1) v = fmaxf(v, __shfl_xor(v, off));
    if ((threadIdx.x & 63) == 0)
        wmax_part[blockIdx.x * 4 + (threadIdx.x >> 6)] = v;  // 4 waves/block
}

// Single-pass MFMA chamfer (verified split math of rounds 4/6, absmax 0.0).
// ROUND-8 RESTRUCTURE: model recalibration (round-3 pipe-saturated kernel =>
// effective clock ~1.3 GHz under load) says rounds 4/6 were VALU-OVERHEAD
// bound: per-block fixed costs (split3 staging, epilogues) recomputed 16x/CU
// because blocks were tiny, plus ~2.8 blocks/CU residency from dispatch drain.
// Changes (math/fragments verbatim):
//  * each block scans CH=4 chunks (1024 cols): grid 1024 = exactly 4 blocks/CU
//    resident in ONE generation (16 waves/CU); A-stage + Af build + min1
//    epilogue amortized 4x.
//  * scanned points for all chunks prefetched to regs up front (global latency
//    hidden under compute); restage = split3 + LDS write only.
//  * Bsh is [16][64] with group-3 zeroed ONCE -> no per-mt cndmask on Bf
//    (lanes 48-63 read real zeros; MFMA inputs bit-identical).
//  * min1 accumulated with v_min3 over tile PAIRS (halves that fmin stream).
//  * min2: per-chunk LDS-combine (round-4 pattern), one atomic per col.
//  * NO full unroll with cross-iteration register arrays (round-7 lesson:
//    m2p[16]+full unroll -> 256 VGPR -> 3x regression).
__global__ __launch_bounds__(256) void chamfer_mfma(
        const float* __restrict__ p1, const float* __restrict__ p2,
        unsigned int* __restrict__ min1, unsigned int* __restrict__ min2) {
    __shared__ s16x8 Ash[16][48];        // 12KB
    __shared__ s16x8 Bsh[16][64];        // 16KB (group 3 zeroed once)
    __shared__ float scr[4 * 16 * 16];   // 4KB min2 wave-combine scratch

    const int bid = blockIdx.x;
    const int b   = bid >> 9;            // 512 blocks per batch
    const int rr  = bid & 511;
    const int ob  = rr >> 3;             // 64 owner blocks
    const int bin = rr & 7;              // 8 scan bins of 1024
    const int nb    = ob * 256;
    const int mbase = bin * (CH * 256);

    const int t = threadIdx.x;
    const int w = t >> 6, l = t & 63;
    const int tl = t >> 4, c15 = t & 15;

    const float* pa = p1 + (size_t)b * N_ * 3;
    const float* pb = p2 + (size_t)b * M_ * 3;
    unsigned int* m1g = min1 + (size_t)b * N_;
    unsigned int* m2g = min2 + (size_t)b * M_;

    // ---- prefetch scanned points for all chunks (global latency up front) --
    float sx[CH], sy[CH], sz[CH];
    #pragma unroll
    for (int c = 0; c < CH; c++) {
        const float* pp = pb + (size_t)(mbase + c * 256 + t) * 3;
        sx[c] = pp[0]; sy[c] = pp[1]; sz[c] = pp[2];
    }

    // ---- stage A (owners) ----
    {
        const float* px = pa + (size_t)(nb + t) * 3;
        s16x8 g0, g1, g2;
        buildA(px[0], px[1], px[2], g0, g1, g2);
        Ash[tl][ 0 + c15] = g0;
        Ash[tl][16 + c15] = g1;
        Ash[tl][32 + c15] = g2;
    }
    // ---- zero Bsh group-3 once; stage B chunk 0 ----
    {
        Bsh[tl][48 + c15] = (s16x8){0, 0, 0, 0, 0, 0, 0, 0};
        s16x8 g0, g1, g2;
        buildB(sx[0], sy[0], sz[0], g0, g1, g2);
        Bsh[tl][ 0 + c15] = g0;
        Bsh[tl][16 + c15] = g1;
        Bsh[tl][32 + c15] = g2;
    }
    __syncthreads();

    const s16x8 zfrag = {0, 0, 0, 0, 0, 0, 0, 0};
    s16x8 Af[4];
    #pragma unroll
    for (int r = 0; r < 4; r++)
        Af[r] = (l < 48) ? Ash[4 * w + r][l] : zfrag;   // group 3 == zeros

    f32x4 mn1v[4];
    #pragma unroll
    for (int r = 0; r < 4; r++)
        mn1v[r] = (f32x4){3.402823466e38f, 3.402823466e38f,
                          3.402823466e38f, 3.402823466e38f};

    const f32x4 zacc = {0.f, 0.f, 0.f, 0.f};

    // ---- chunk loop ----
    #pragma unroll
    for (int c = 0; c < CH; c++) {
        // 8 tile-pairs; min1 accumulated pairwise with v_min3
        #pragma unroll 2
        for (int mp = 0; mp < 8; mp++) {
            s16x8 Bf0 = Bsh[2 * mp][l];
            s16x8 Bf1 = Bsh[2 * mp + 1][l];
            float p20 = 3.402823466e38f, p21 = 3.402823466e38f;
            #pragma unroll
            for (int r = 0; r < 4; r++) {
                f32x4 aA = __builtin_amdgcn_mfma_f32_16x16x32_bf16(Af[r], Bf0, zacc, 0, 0, 0);
                f32x4 aB = __builtin_amdgcn_mfma_f32_16x16x32_bf16(Af[r], Bf1, zacc, 0, 0, 0);
                mn1v[r].x = min3f(mn1v[r].x, aA.x, aB.x);
                mn1v[r].y = min3f(mn1v[r].y, aA.y, aB.y);
                mn1v[r].z = min3f(mn1v[r].z, aA.z, aB.z);
                mn1v[r].w = min3f(mn1v[r].w, aA.w, aB.w);
                p20 = fminf(p20, fminf(min3f(aA.x, aA.y, aA.z), aA.w));
                p21 = fminf(p21, fminf(min3f(aB.x, aB.y, aB.z), aB.w));
            }
            // cross row-group col-min (col = l&15), store wave partial
            p20 = fminf(p20, __shfl_xor(p20, 16));
            p20 = fminf(p20, __shfl_xor(p20, 32));
            p21 = fminf(p21, __shfl_xor(p21, 16));
            p21 = fminf(p21, __shfl_xor(p21, 32));
            if (l < 16) {
                scr[(w * 16 + 2 * mp) * 16 + l]     = p20;
                scr[(w * 16 + 2 * mp + 1) * 16 + l] = p21;
            }
        }
        __syncthreads();
        // combine 4 wave partials per col -> one atomic per col (256/chunk)
        {
            float v = fminf(fminf(scr[(0 * 16 + tl) * 16 + c15],
                                  scr[(1 * 16 + tl) * 16 + c15]),
                            fminf(scr[(2 * 16 + tl) * 16 + c15],
                                  scr[(3 * 16 + tl) * 16 + c15]));
            atomicMin(&m2g[mbase + c * 256 + tl * 16 + c15], __float_as_uint(v));
        }
        // restage next chunk (groups 0-2 only; group-3 stays zero)
        if (c < CH - 1) {
            s16x8 g0, g1, g2;
            buildB(sx[c + 1], sy[c + 1], sz[c + 1], g0, g1, g2);
            Bsh[tl][ 0 + c15] = g0;
            Bsh[tl][16 + c15] = g1;
            Bsh[tl][32 + c15] = g2;
        }
        __syncthreads();
    }

    // ---- epilogue: min1 (reduce over the 16 cols held across lanes l&15) ----
    #pragma unroll
    for (int r = 0; r < 4; r++) {
        #pragma unroll
        for (int q = 0; q < 4; q++) {
            float v = mn1v[r][q];
            v = fminf(v, __shfl_xor(v, 1));
            v = fminf(v, __shfl_xor(v, 2));
            v = fminf(v, __shfl_xor(v, 4));
            v = fminf(v, __shfl_xor(v, 8));
            if ((l & 15) == 0) {
                int row = nb + (4 * w + r) * 16 + (l >> 4) * 4 + q;
                // distances non-negative: float bits order as uint
                atomicMin(&m1g[row], __float_as_uint(v));
            }
        }
    }
}

__global__ __launch_bounds__(1024) void finalize_kernel(
        const float* __restrict__ wts,
        const float* __restrict__ min1,
        const float* __restrict__ min2,
        const float* __restrict__ wmax_part,
        float* __restrict__ out) {
    __shared__ float red[16];
    int b = blockIdx.x;
    const float* wb = wts + b * N_;
    const float* m1 = min1 + b * N_;
    const float* m2 = min2 + b * M_;

    float lmax = (threadIdx.x < 256) ? wmax_part[b * 256 + threadIdx.x]
                                     : -3.402823466e38f;
    float gmax = blk_reduce_max(lmax, red);

    float se = 0.0f, swm = 0.0f;
    for (int i = threadIdx.x; i < N_ / 4; i += blockDim.x) {
        f32x4 w4 = ((const f32x4*)wb)[i];
        f32x4 m4 = ((const f32x4*)m1)[i];
        #pragma unroll
        for (int k = 0; k < 4; k++) {
            float e = expf(w4[k] - gmax);
            se += e;
            swm += e * m4[k];
        }
    }
    float tse = blk_reduce_sum(se, red);
    float tswm = blk_reduce_sum(swm, red);

    float sm2 = 0.0f;
    for (int i = threadIdx.x; i < M_ / 4; i += blockDim.x) {
        f32x4 m4 = ((const f32x4*)m2)[i];
        sm2 += (m4.x + m4.y) + (m4.z + m4.w);
    }
    float tsm2 = blk_reduce_sum(sm2, red);

    if (threadIdx.x == 0)
        atomicAdd(out, (tswm / tse + tsm2 * (1.0f / (float)M_)) * (1.0f / (float)B_));
}

// ---------------- launch ----------------

extern "C" void kernel_launch(void* const* d_in, const int* in_sizes, int n_in,
                              void* d_out, int out_size, void* d_ws, size_t ws_size,
                              hipStream_t stream) {
    const float* p1  = (const float*)d_in[0];  // (B, N, 3)
    const float* p2  = (const float*)d_in[1];  // (B, M, 3)
    const float* wts = (const float*)d_in[2];  // (B, N)
    float* out = (float*)d_out;

    unsigned int* min1 = (unsigned int*)d_ws;        // B*N
    unsigned int* min2 = min1 + B_ * N_;             // B*M
    float* wmax_part = (float*)(min2 + B_ * M_);     // 128 blocks * 4 waves = 512

    init_ws<<<dim3((B_ * N_) / 256), dim3(256), 0, stream>>>(wts, min1, min2,
                                                             wmax_part, out);
    // 2 batches * 64 owner-blocks * 8 scan-bins = 1024 blocks (4/CU, 1 generation)
    chamfer_mfma<<<dim3(B_ * 64 * (M_ / (CH * 256))), dim3(256), 0, stream>>>(
        p1, p2, min1, min2);
    finalize_kernel<<<dim3(B_), dim3(1024), 0, stream>>>(
        wts, (const float*)min1, (const float*)min2, wmax_part, out);
}

// Round 9
// 48.438 us; speedup vs baseline: 3.2300x; 1.0399x over previous
//
#include <hip/hip_runtime.h>

#define B_ 2
#define N_ 16384
#define M_ 8192
#define CH 4                      // scan chunks per block (4*256 = 1024 cols)

typedef float f32x4 __attribute__((ext_vector_type(4)));
typedef short s16x8 __attribute__((ext_vector_type(8)));

__device__ inline float min3f(float a, float b, float c) {
    float d;
    asm("v_min3_f32 %0, %1, %2, %3" : "=v"(d) : "v"(a), "v"(b), "v"(c));
    return d;
}

// RNE f32 -> bf16 (bits)
__device__ inline unsigned short f2bf(float f) {
    unsigned int u = __float_as_uint(f);
    u += 0x7FFFu + ((u >> 16) & 1u);
    return (unsigned short)(u >> 16);
}
__device__ inline float bf2f(unsigned short h) {
    return __uint_as_float(((unsigned int)h) << 16);
}
// 3-way bf16 split: v ~= h + m + l to ~2^-24 rel
__device__ inline void split3(float v, unsigned short& hb, unsigned short& mb,
                              unsigned short& lb) {
    hb = f2bf(v);
    float r1 = v - bf2f(hb);
    mb = f2bf(r1);
    float r2 = r1 - bf2f(mb);
    lb = f2bf(r2);
}

#define ONE_BF ((short)0x3F80)

// fragment builders — verbatim slot maps from the verified rounds 4/6/8 kernel
__device__ inline void buildA(float x0, float x1, float x2,
                              s16x8& g0, s16x8& g1, s16x8& g2) {
    float sq = fmaf(x0, x0, fmaf(x1, x1, x2 * x2));
    unsigned short uh[3], um[3], ul[3], s1[3];
    split3(-2.f * x0, uh[0], um[0], ul[0]);
    split3(-2.f * x1, uh[1], um[1], ul[1]);
    split3(-2.f * x2, uh[2], um[2], ul[2]);
    split3(sq, s1[0], s1[1], s1[2]);
    g0 = (s16x8){(short)uh[0], (short)uh[1], (short)uh[2], (short)uh[0],
                 (short)uh[1], (short)uh[2], (short)um[0], (short)um[1]};
    g1 = (s16x8){(short)um[2], (short)uh[0], (short)uh[1], (short)uh[2],
                 (short)ul[0], (short)ul[1], (short)ul[2], (short)um[0]};
    g2 = (s16x8){(short)um[1], (short)um[2], (short)s1[0], (short)s1[1],
                 (short)s1[2], ONE_BF, ONE_BF, ONE_BF};
}
__device__ inline void buildB(float y0, float y1, float y2,
                              s16x8& g0, s16x8& g1, s16x8& g2) {
    float sq = fmaf(y0, y0, fmaf(y1, y1, y2 * y2));
    unsigned short yh[3], ym[3], yl[3], s2[3];
    split3(y0, yh[0], ym[0], yl[0]);
    split3(y1, yh[1], ym[1], yl[1]);
    split3(y2, yh[2], ym[2], yl[2]);
    split3(sq, s2[0], s2[1], s2[2]);
    g0 = (s16x8){(short)yh[0], (short)yh[1], (short)yh[2], (short)ym[0],
                 (short)ym[1], (short)ym[2], (short)yh[0], (short)yh[1]};
    g1 = (s16x8){(short)yh[2], (short)yl[0], (short)yl[1], (short)yl[2],
                 (short)yh[0], (short)yh[1], (short)yh[2], (short)ym[0]};
    g2 = (s16x8){(short)ym[1], (short)ym[2], ONE_BF, ONE_BF, ONE_BF,
                 (short)s2[0], (short)s2[1], (short)s2[2]};
}

// ---------------- reductions ----------------

__device__ inline float blk_reduce_max(float v, float* red) {
    #pragma unroll
    for (int off = 32; off; off >>= 1) v = fmaxf(v, __shfl_xor(v, off));
    int wid = threadIdx.x >> 6;
    int lane = threadIdx.x & 63;
    int nw = blockDim.x >> 6;
    if (lane == 0) red[wid] = v;
    __syncthreads();
    if (wid == 0) {
        v = (lane < nw) ? red[lane] : -3.402823466e38f;
        #pragma unroll
        for (int off = 32; off; off >>= 1) v = fmaxf(v, __shfl_xor(v, off));
        if (lane == 0) red[0] = v;
    }
    __syncthreads();
    v = red[0];
    __syncthreads();
    return v;
}

__device__ inline float blk_reduce_sum(float v, float* red) {
    #pragma unroll
    for (int off = 32; off; off >>= 1) v += __shfl_xor(v, off);
    int wid = threadIdx.x >> 6;
    int lane = threadIdx.x & 63;
    int nw = blockDim.x >> 6;
    if (lane == 0) red[wid] = v;
    __syncthreads();
    if (wid == 0) {
        v = (lane < nw) ? red[lane] : 0.0f;
        #pragma unroll
        for (int off = 32; off; off >>= 1) v += __shfl_xor(v, off);
        if (lane == 0) red[0] = v;
    }
    __syncthreads();
    v = red[0];
    __syncthreads();
    return v;
}

// ---------------- kernels ----------------

// grid 128 blocks. Init ws, weight wave-maxes, AND precompute all MFMA
// fragments ONCE (round-9 change): round-8 audit showed ~40% of the hot
// kernel's VALU stream was split3+packing, rebuilt for the same point by
// every block scanning it (B-frags rebuilt 64x each). Here each point is
// built exactly once; the hot kernel just loads 16B quads.
// Fragment layout: plane-major [b][group][point] so staging is coalesced.
__global__ __launch_bounds__(256) void init_ws(const float* __restrict__ wts,
                                               const float* __restrict__ p1,
                                               const float* __restrict__ p2,
                                               unsigned int* min1, unsigned int* min2,
                                               float* __restrict__ wmax_part,
                                               s16x8* __restrict__ Afrag,
                                               s16x8* __restrict__ Bfrag,
                                               float* out) {
    int i = blockIdx.x * 256 + threadIdx.x;   // [0, B_*N_)
    min1[i] = 0x7F7FFFFFu;                    // FLT_MAX bits
    if (i < B_ * M_) min2[i] = 0x7F7FFFFFu;
    if (i == 0) out[0] = 0.0f;

    float v = wts[i];
    #pragma unroll
    for (int off = 32; off; off >>= 1) v = fmaxf(v, __shfl_xor(v, off));
    if ((threadIdx.x & 63) == 0)
        wmax_part[blockIdx.x * 4 + (threadIdx.x >> 6)] = v;  // 4 waves/block

    // A fragment for p1 point i
    {
        int b = i >> 14, n = i & (N_ - 1);
        const float* px = p1 + (size_t)i * 3;
        s16x8 g0, g1, g2;
        buildA(px[0], px[1], px[2], g0, g1, g2);
        Afrag[(b * 3 + 0) * N_ + n] = g0;
        Afrag[(b * 3 + 1) * N_ + n] = g1;
        Afrag[(b * 3 + 2) * N_ + n] = g2;
    }
    // B fragment for p2 point i
    if (i < B_ * M_) {
        int b = i >> 13, m = i & (M_ - 1);
        const float* py = p2 + (size_t)i * 3;
        s16x8 g0, g1, g2;
        buildB(py[0], py[1], py[2], g0, g1, g2);
        Bfrag[(b * 3 + 0) * M_ + m] = g0;
        Bfrag[(b * 3 + 1) * M_ + m] = g1;
        Bfrag[(b * 3 + 2) * M_ + m] = g2;
    }
}

// Single-pass MFMA chamfer (fragment bytes & math verbatim rounds 4/6/8,
// absmax 0.0). ROUND-9: staging = pure loads of precomputed fragments.
//  * LDS planes: Apl[3][256] (12KB), Bpl[4][256] (16KB, plane 3 zeroed once
//    -> lanes 48-63 hit real zeros BY ADDRESS, no in-loop cndmask),
//    scr 4KB. Total 32KB -> 5 blocks/CU static; grid 1024 = 4/CU.
//  * per-chunk restage: 3 dwordx4 loads (issued BEFORE compute of the
//    previous chunk -> HBM latency hides under MFMA, T14) + 3 ds_write_b128.
//    No split3/packing in this kernel at all.
//  * p2 fold tightened: min3(p, min3(x,y,z), w) = 2 ops (was 3).
//  * round-7 lesson respected: no cross-iteration register arrays.
__global__ __launch_bounds__(256) void chamfer_mfma(
        const s16x8* __restrict__ Afrag, const s16x8* __restrict__ Bfrag,
        unsigned int* __restrict__ min1, unsigned int* __restrict__ min2) {
    __shared__ s16x8 Apl[3][256];        // 12KB
    __shared__ s16x8 Bpl[4][256];        // 16KB (plane 3 = zeros)
    __shared__ float scr[4 * 16 * 16];   // 4KB min2 wave-combine scratch

    const int bid = blockIdx.x;
    const int b   = bid >> 9;            // 512 blocks per batch
    const int rr  = bid & 511;
    const int ob  = rr >> 3;             // 64 owner blocks
    const int bin = rr & 7;              // 8 scan bins of 1024
    const int nb    = ob * 256;
    const int mbase = bin * (CH * 256);

    const int t = threadIdx.x;
    const int w = t >> 6, l = t & 63;
    const int tl = t >> 4, c15 = t & 15;
    const s16x8 zfrag = {0, 0, 0, 0, 0, 0, 0, 0};

    const s16x8* Ab = Afrag + (size_t)(b * 3) * N_;
    const s16x8* Bb = Bfrag + (size_t)(b * 3) * M_;
    unsigned int* m1g = min1 + (size_t)b * N_;
    unsigned int* m2g = min2 + (size_t)b * M_;

    // ---- stage A planes + zero B plane 3 + stage B chunk 0 ----
    {
        s16x8 a0 = Ab[0 * N_ + nb + t];
        s16x8 a1 = Ab[1 * N_ + nb + t];
        s16x8 a2 = Ab[2 * N_ + nb + t];
        s16x8 b0 = Bb[0 * M_ + mbase + t];
        s16x8 b1 = Bb[1 * M_ + mbase + t];
        s16x8 b2 = Bb[2 * M_ + mbase + t];
        Apl[0][t] = a0;
        Apl[1][t] = a1;
        Apl[2][t] = a2;
        Bpl[3][t] = zfrag;
        Bpl[0][t] = b0;
        Bpl[1][t] = b1;
        Bpl[2][t] = b2;
    }
    __syncthreads();

    s16x8 Af[4];
    #pragma unroll
    for (int r = 0; r < 4; r++)
        Af[r] = (l < 48) ? Apl[l >> 4][(4 * w + r) * 16 + (l & 15)] : zfrag;

    f32x4 mn1v[4];
    #pragma unroll
    for (int r = 0; r < 4; r++)
        mn1v[r] = (f32x4){3.402823466e38f, 3.402823466e38f,
                          3.402823466e38f, 3.402823466e38f};

    const f32x4 zacc = {0.f, 0.f, 0.f, 0.f};
    const s16x8* Bflat = &Bpl[0][0];
    const int boff = (l >> 4) * 256 + (l & 15);   // plane 3 for l>=48 -> zeros

    // ---- chunk loop ----
    for (int c = 0; c < CH; c++) {
        // prefetch next chunk to regs; loads issue now, land under compute
        s16x8 pb0, pb1, pb2;
        if (c + 1 < CH) {
            int src = mbase + (c + 1) * 256 + t;
            pb0 = Bb[0 * M_ + src];
            pb1 = Bb[1 * M_ + src];
            pb2 = Bb[2 * M_ + src];
        }
        // 8 tile-pairs; min1 accumulated pairwise with v_min3
        #pragma unroll 2
        for (int mp = 0; mp < 8; mp++) {
            s16x8 Bf0 = Bflat[boff + (2 * mp) * 16];
            s16x8 Bf1 = Bflat[boff + (2 * mp + 1) * 16];
            float p20 = 3.402823466e38f, p21 = 3.402823466e38f;
            #pragma unroll
            for (int r = 0; r < 4; r++) {
                f32x4 aA = __builtin_amdgcn_mfma_f32_16x16x32_bf16(Af[r], Bf0, zacc, 0, 0, 0);
                f32x4 aB = __builtin_amdgcn_mfma_f32_16x16x32_bf16(Af[r], Bf1, zacc, 0, 0, 0);
                mn1v[r].x = min3f(mn1v[r].x, aA.x, aB.x);
                mn1v[r].y = min3f(mn1v[r].y, aA.y, aB.y);
                mn1v[r].z = min3f(mn1v[r].z, aA.z, aB.z);
                mn1v[r].w = min3f(mn1v[r].w, aA.w, aB.w);
                p20 = min3f(p20, min3f(aA.x, aA.y, aA.z), aA.w);
                p21 = min3f(p21, min3f(aB.x, aB.y, aB.z), aB.w);
            }
            // cross row-group col-min (col = l&15), store wave partial
            p20 = fminf(p20, __shfl_xor(p20, 16));
            p20 = fminf(p20, __shfl_xor(p20, 32));
            p21 = fminf(p21, __shfl_xor(p21, 16));
            p21 = fminf(p21, __shfl_xor(p21, 32));
            if (l < 16) {
                scr[(w * 16 + 2 * mp) * 16 + l]     = p20;
                scr[(w * 16 + 2 * mp + 1) * 16 + l] = p21;
            }
        }
        __syncthreads();   // scr complete; all waves done reading Bpl
        // combine 4 wave partials per col -> one atomic per col (256/chunk)
        {
            float v = fminf(fminf(scr[(0 * 16 + tl) * 16 + c15],
                                  scr[(1 * 16 + tl) * 16 + c15]),
                            fminf(scr[(2 * 16 + tl) * 16 + c15],
                                  scr[(3 * 16 + tl) * 16 + c15]));
            atomicMin(&m2g[mbase + c * 256 + tl * 16 + c15], __float_as_uint(v));
        }
        // restage next chunk from the prefetched regs
        if (c + 1 < CH) {
            Bpl[0][t] = pb0;
            Bpl[1][t] = pb1;
            Bpl[2][t] = pb2;
        }
        __syncthreads();   // Bpl(c+1) ready; scr reads done before overwrite
    }

    // ---- epilogue: min1 (reduce over the 16 cols held across lanes l&15) ----
    #pragma unroll
    for (int r = 0; r < 4; r++) {
        #pragma unroll
        for (int q = 0; q < 4; q++) {
            float v = mn1v[r][q];
            v = fminf(v, __shfl_xor(v, 1));
            v = fminf(v, __shfl_xor(v, 2));
            v = fminf(v, __shfl_xor(v, 4));
            v = fminf(v, __shfl_xor(v, 8));
            if ((l & 15) == 0) {
                int row = nb + (4 * w + r) * 16 + (l >> 4) * 4 + q;
                // distances non-negative: float bits order as uint
                atomicMin(&m1g[row], __float_as_uint(v));
            }
        }
    }
}

__global__ __launch_bounds__(1024) void finalize_kernel(
        const float* __restrict__ wts,
        const float* __restrict__ min1,
        const float* __restrict__ min2,
        const float* __restrict__ wmax_part,
        float* __restrict__ out) {
    __shared__ float red[16];
    int b = blockIdx.x;
    const float* wb = wts + b * N_;
    const float* m1 = min1 + b * N_;
    const float* m2 = min2 + b * M_;

    float lmax = (threadIdx.x < 256) ? wmax_part[b * 256 + threadIdx.x]
                                     : -3.402823466e38f;
    float gmax = blk_reduce_max(lmax, red);

    float se = 0.0f, swm = 0.0f;
    for (int i = threadIdx.x; i < N_ / 4; i += blockDim.x) {
        f32x4 w4 = ((const f32x4*)wb)[i];
        f32x4 m4 = ((const f32x4*)m1)[i];
        #pragma unroll
        for (int k = 0; k < 4; k++) {
            float e = expf(w4[k] - gmax);
            se += e;
            swm += e * m4[k];
        }
    }
    float tse = blk_reduce_sum(se, red);
    float tswm = blk_reduce_sum(swm, red);

    float sm2 = 0.0f;
    for (int i = threadIdx.x; i < M_ / 4; i += blockDim.x) {
        f32x4 m4 = ((const f32x4*)m2)[i];
        sm2 += (m4.x + m4.y) + (m4.z + m4.w);
    }
    float tsm2 = blk_reduce_sum(sm2, red);

    if (threadIdx.x == 0)
        atomicAdd(out, (tswm / tse + tsm2 * (1.0f / (float)M_)) * (1.0f / (float)B_));
}

// ---------------- launch ----------------

extern "C" void kernel_launch(void* const* d_in, const int* in_sizes, int n_in,
                              void* d_out, int out_size, void* d_ws, size_t ws_size,
                              hipStream_t stream) {
    const float* p1  = (const float*)d_in[0];  // (B, N, 3)
    const float* p2  = (const float*)d_in[1];  // (B, M, 3)
    const float* wts = (const float*)d_in[2];  // (B, N)
    float* out = (float*)d_out;

    // workspace layout (16B-aligned sections):
    //   min1: B*N u32 (128KB) | min2: B*M u32 (64KB) | wmax: 512 f32 (2KB pad->4KB)
    //   Afrag: B*3*N s16x8 (1.5MB) | Bfrag: B*3*M s16x8 (768KB)   total ~2.5MB
    unsigned int* min1 = (unsigned int*)d_ws;            // B*N
    unsigned int* min2 = min1 + B_ * N_;                 // B*M
    float* wmax_part = (float*)(min2 + B_ * M_);         // 512 floats
    char* frag_base = (char*)d_ws + 196608 + 4096;       // 16B aligned
    s16x8* Afrag = (s16x8*)frag_base;                    // B*3*N quads
    s16x8* Bfrag = Afrag + B_ * 3 * N_;                  // B*3*M quads

    init_ws<<<dim3((B_ * N_) / 256), dim3(256), 0, stream>>>(
        wts, p1, p2, min1, min2, wmax_part, Afrag, Bfrag, out);
    // 2 batches * 64 owner-blocks * 8 scan-bins = 1024 blocks (4/CU)
    chamfer_mfma<<<dim3(B_ * 64 * (M_ / (CH * 256))), dim3(256), 0, stream>>>(
        Afrag, Bfrag, min1, min2);
    finalize_kernel<<<dim3(B_), dim3(1024), 0, stream>>>(
        wts, (const float*)min1, (const float*)min2, wmax_part, out);
}